// Round 1
// baseline (203.746 us; speedup 1.0000x reference)
//
#include <hip/hip_runtime.h>
#include <stdint.h>

#define NB 2
#define NS 2048
#define ND 1024
#define NH 16
#define NHD 64
#define NM (NB*NS)   // 4096

typedef __bf16 bf16;
typedef float f32x4 __attribute__((ext_vector_type(4)));
typedef __bf16 bf16x8 __attribute__((ext_vector_type(8)));
typedef __bf16 bf16x4 __attribute__((ext_vector_type(4)));

#define MFMA16(a,b,c) __builtin_amdgcn_mfma_f32_16x16x32_bf16(a,b,c,0,0,0)

__device__ __forceinline__ void gld_lds16(const bf16* g, bf16* l) {
  __builtin_amdgcn_global_load_lds((const __attribute__((address_space(1))) void*)g,
                                   (__attribute__((address_space(3))) void*)l,
                                   16, 0, 0);
}

// ---------------- fp32 -> bf16 conversion (vectorized x4) ----------------
__global__ __launch_bounds__(256) void cvt_bf16(const float* __restrict__ src,
                                                bf16* __restrict__ dst, int n4) {
  int i = blockIdx.x * blockDim.x + threadIdx.x;
  if (i >= n4) return;
  float4 v = ((const float4*)src)[i];
  bf16x4 o = { (bf16)v.x, (bf16)v.y, (bf16)v.z, (bf16)v.w };
  ((bf16x4*)dst)[i] = o;
}

// ---------------- NT GEMM: C[m,n] = sum_k A[m,k]*W[n,k] + bias[n] --------
// MODE 0: QKV projection, bf16 out scattered to [B,H,S,HD] (z = tensor 0..2)
// MODE 1: output projection, fp32 out row-major [M, D]
template<int MODE>
__global__ __launch_bounds__(256)
void gemm_nt(const bf16* __restrict__ A, const bf16* __restrict__ W,
             const float* __restrict__ b0, const float* __restrict__ b1,
             const float* __restrict__ b2,
             bf16* __restrict__ obf, float* __restrict__ of) {
  constexpr int K = ND;
  __shared__ __align__(16) bf16 As[128 * 32];
  __shared__ __align__(16) bf16 Bs[128 * 32];
  const int tid = threadIdx.x;
  const int w = tid >> 6, lane = tid & 63;
  const int nt = blockIdx.x, mt = blockIdx.y, t = blockIdx.z;
  const bf16* Ab = A + (size_t)t * ((size_t)NM * K);
  const bf16* Wb = W + (size_t)t * ((size_t)ND * K);
  const float* bias = (t == 0) ? b0 : (t == 1) ? b1 : b2;
  const int wr = (w >> 1) * 64, wc = (w & 1) * 64;
  f32x4 acc[4][4] = {};
  const bf16* ga = Ab + (size_t)(mt * 128 + (tid >> 2)) * K + (tid & 3) * 8;
  const bf16* gb = Wb + (size_t)(nt * 128 + (tid >> 2)) * K + (tid & 3) * 8;
  bf16* lA = As + w * 512;   // wave-uniform LDS base (gld_lds writes base + lane*16)
  bf16* lB = Bs + w * 512;
  for (int k0 = 0; k0 < K; k0 += 32) {
    __syncthreads();
    gld_lds16(ga + k0, lA);
    gld_lds16(ga + (size_t)64 * K + k0, lA + 64 * 32);
    gld_lds16(gb + k0, lB);
    gld_lds16(gb + (size_t)64 * K + k0, lB + 64 * 32);
    __syncthreads();   // compiler drains vmcnt(0) before s_barrier -> LDS ready
    bf16x8 af[4], bfr[4];
#pragma unroll
    for (int i = 0; i < 4; ++i) {
      af[i]  = *(const bf16x8*)&As[(wr + i * 16 + (lane & 15)) * 32 + (lane >> 4) * 8];
      bfr[i] = *(const bf16x8*)&Bs[(wc + i * 16 + (lane & 15)) * 32 + (lane >> 4) * 8];
    }
#pragma unroll
    for (int i = 0; i < 4; ++i)
#pragma unroll
      for (int j = 0; j < 4; ++j)
        acc[i][j] = MFMA16(af[i], bfr[j], acc[i][j]);
  }
#pragma unroll
  for (int i = 0; i < 4; ++i) {
#pragma unroll
    for (int j = 0; j < 4; ++j) {
      const int gcol = nt * 128 + wc + j * 16 + (lane & 15);
      const float bv = bias[gcol];
#pragma unroll
      for (int r = 0; r < 4; ++r) {
        const int grow = mt * 128 + wr + i * 16 + (lane >> 4) * 4 + r;
        const float v = acc[i][j][r] + bv;
        if (MODE == 0) {
          const int b = grow >> 11, s = grow & (NS - 1);
          const int h = gcol >> 6, hd = gcol & 63;
          obf[(size_t)t * ((size_t)NM * ND) +
              (((size_t)(b * NH + h) * NS + s) * NHD + hd)] = (bf16)v;
        } else {
          of[(size_t)grow * ND + gcol] = v;
        }
      }
    }
  }
}

// ---------------- RoPE in place on [BH, S, HD] bf16 ----------------------
template<bool SC>
__global__ __launch_bounds__(256)
void rope_k(bf16* __restrict__ x, const float* __restrict__ fc,
            const float* __restrict__ fs) {
  int idx = blockIdx.x * blockDim.x + threadIdx.x;   // BH*S*32 = 2^21 threads
  int i = idx & 31;
  int s = (idx >> 5) & (NS - 1);
  float c = fc[s * 32 + i], sn = fs[s * 32 + i];
  bf16* p = x + (size_t)idx * 2;
  float xr = (float)p[0], xi = (float)p[1];
  float r = xr * c - xi * sn;
  float m = xr * sn + xi * c;
  if (SC) { r *= 0.125f; m *= 0.125f; }   // fold in 1/sqrt(HD)
  p[0] = (bf16)r;
  p[1] = (bf16)m;
}

// ---------------- V transpose: [BH, S, 64] -> [BH, 64, S] ----------------
__global__ __launch_bounds__(256)
void transpose_v(const bf16* __restrict__ v, bf16* __restrict__ vt) {
  __shared__ __align__(16) bf16 t[64][72];
  const int s0 = blockIdx.x * 64;
  const int bh = blockIdx.y;
  const bf16* src = v + ((size_t)bh * NS + s0) * NHD;
#pragma unroll
  for (int it = 0; it < 2; ++it) {
    int slot = threadIdx.x + it * 256;
    int r = slot >> 3, c8 = (slot & 7) * 8;
    *(bf16x8*)&t[r][c8] = *(const bf16x8*)&src[(size_t)r * NHD + c8];
  }
  __syncthreads();
  bf16* dst = vt + (size_t)bh * NHD * NS + s0;
#pragma unroll
  for (int it = 0; it < 2; ++it) {
    int slot = threadIdx.x + it * 256;
    int r = slot >> 3, c8 = (slot & 7) * 8;   // r = hd row of output, c8 = s offset
    bf16x8 vv;
#pragma unroll
    for (int e = 0; e < 8; ++e) vv[e] = t[c8 + e][r];
    *(bf16x8*)&dst[(size_t)r * NS + c8] = vv;
  }
}

// ---------------- flash attention, causal, 4 waves x 32 q-rows ----------
__global__ __launch_bounds__(256)
void attn_k(const bf16* __restrict__ q, const bf16* __restrict__ k,
            const bf16* __restrict__ vt, bf16* __restrict__ out) {
  __shared__ __align__(16) bf16 Ks[64][72];       // [k-pos][hd], padded
  __shared__ __align__(16) bf16 Vs[64][72];       // [hd][k-pos], padded
  __shared__ __align__(16) bf16 P[4][32][72];     // per-wave P tile
  const int w = threadIdx.x >> 6, lane = threadIdx.x & 63;
  const int qt = blockIdx.x, bh = blockIdx.y;
  const int b = bh >> 4, h = bh & (NH - 1);
  const int q0 = qt * 128 + w * 32;

  const bf16* qb = q + ((size_t)bh * NS + q0) * NHD;
  bf16x8 qf[2][2];
#pragma unroll
  for (int rb = 0; rb < 2; ++rb)
#pragma unroll
    for (int ch = 0; ch < 2; ++ch)
      qf[rb][ch] = *(const bf16x8*)&qb[(size_t)(rb * 16 + (lane & 15)) * NHD +
                                       ch * 32 + (lane >> 4) * 8];

  f32x4 o[2][4] = {};
  float mrow[2][4], lrow[2][4];
#pragma unroll
  for (int rb = 0; rb < 2; ++rb)
#pragma unroll
    for (int r = 0; r < 4; ++r) { mrow[rb][r] = -1e30f; lrow[rb][r] = 0.f; }

  const bf16* kb = k + (size_t)bh * NS * NHD;
  const bf16* vb = vt + (size_t)bh * NHD * NS;
  const int ktiles = 2 * qt + 2;

  for (int kt = 0; kt < ktiles; ++kt) {
    const int kk0 = kt * 64;
    __syncthreads();
#pragma unroll
    for (int it = 0; it < 2; ++it) {
      int slot = threadIdx.x + it * 256;
      int r = slot >> 3, c8 = (slot & 7) * 8;
      *(bf16x8*)&Ks[r][c8] = *(const bf16x8*)&kb[(size_t)(kk0 + r) * NHD + c8];
      *(bf16x8*)&Vs[r][c8] = *(const bf16x8*)&vb[(size_t)r * NS + kk0 + c8];
    }
    __syncthreads();
    if (kk0 > q0 + 31) continue;   // tile fully masked for this wave (barriers stay uniform)

    const f32x4 vzero = {0.f, 0.f, 0.f, 0.f};
    f32x4 sc[2][4];
#pragma unroll
    for (int rb = 0; rb < 2; ++rb)
#pragma unroll
      for (int cb = 0; cb < 4; ++cb) sc[rb][cb] = vzero;

#pragma unroll
    for (int ch = 0; ch < 2; ++ch) {
#pragma unroll
      for (int cb = 0; cb < 4; ++cb) {
        bf16x8 kf = *(const bf16x8*)&Ks[cb * 16 + (lane & 15)][ch * 32 + (lane >> 4) * 8];
        sc[0][cb] = MFMA16(qf[0][ch], kf, sc[0][cb]);
        sc[1][cb] = MFMA16(qf[1][ch], kf, sc[1][cb]);
      }
    }

    if (kk0 + 63 > q0) {   // diagonal tile for this wave -> elementwise causal mask
#pragma unroll
      for (int rb = 0; rb < 2; ++rb)
#pragma unroll
        for (int cb = 0; cb < 4; ++cb)
#pragma unroll
          for (int r = 0; r < 4; ++r) {
            int qi = q0 + rb * 16 + (lane >> 4) * 4 + r;
            int kj = kk0 + cb * 16 + (lane & 15);
            if (kj > qi) sc[rb][cb][r] = -1e30f;
          }
    }

#pragma unroll
    for (int rb = 0; rb < 2; ++rb) {
      float tm[4];
#pragma unroll
      for (int r = 0; r < 4; ++r)
        tm[r] = fmaxf(fmaxf(sc[rb][0][r], sc[rb][1][r]),
                      fmaxf(sc[rb][2][r], sc[rb][3][r]));
#pragma unroll
      for (int off = 1; off < 16; off <<= 1)
#pragma unroll
        for (int r = 0; r < 4; ++r)
          tm[r] = fmaxf(tm[r], __shfl_xor(tm[r], off));
#pragma unroll
      for (int r = 0; r < 4; ++r) {
        float mn = fmaxf(mrow[rb][r], tm[r]);
        float scl = __expf(mrow[rb][r] - mn);
        mrow[rb][r] = mn;
        lrow[rb][r] *= scl;
#pragma unroll
        for (int hb = 0; hb < 4; ++hb) o[rb][hb][r] *= scl;
        float ps = 0.f;
#pragma unroll
        for (int cb = 0; cb < 4; ++cb) {
          float p = __expf(sc[rb][cb][r] - mn);
          ps += p;
          P[w][rb * 16 + (lane >> 4) * 4 + r][cb * 16 + (lane & 15)] = (bf16)p;
        }
        lrow[rb][r] += ps;   // per-lane partial; reduced across 16 lanes at the end
      }
    }

#pragma unroll
    for (int ch = 0; ch < 2; ++ch) {
      bf16x8 pa0 = *(const bf16x8*)&P[w][(lane & 15)][ch * 32 + (lane >> 4) * 8];
      bf16x8 pa1 = *(const bf16x8*)&P[w][16 + (lane & 15)][ch * 32 + (lane >> 4) * 8];
#pragma unroll
      for (int hb = 0; hb < 4; ++hb) {
        bf16x8 vf = *(const bf16x8*)&Vs[hb * 16 + (lane & 15)][ch * 32 + (lane >> 4) * 8];
        o[0][hb] = MFMA16(pa0, vf, o[0][hb]);
        o[1][hb] = MFMA16(pa1, vf, o[1][hb]);
      }
    }
  }

#pragma unroll
  for (int rb = 0; rb < 2; ++rb) {
    float ls[4];
#pragma unroll
    for (int r = 0; r < 4; ++r) ls[r] = lrow[rb][r];
#pragma unroll
    for (int off = 1; off < 16; off <<= 1)
#pragma unroll
      for (int r = 0; r < 4; ++r) ls[r] += __shfl_xor(ls[r], off);
#pragma unroll
    for (int r = 0; r < 4; ++r) {
      float inv = 1.f / ls[r];
      int s = q0 + rb * 16 + (lane >> 4) * 4 + r;
#pragma unroll
      for (int hb = 0; hb < 4; ++hb) {
        int gcol = h * NHD + hb * 16 + (lane & 15);
        out[(size_t)(b * NS + s) * ND + gcol] = (bf16)(o[rb][hb][r] * inv);
      }
    }
  }
}

// -------------------------------------------------------------------------
extern "C" void kernel_launch(void* const* d_in, const int* in_sizes, int n_in,
                              void* d_out, int out_size, void* d_ws, size_t ws_size,
                              hipStream_t stream) {
  const float* Q  = (const float*)d_in[0];
  const float* K  = (const float*)d_in[1];
  const float* V  = (const float*)d_in[2];
  // d_in[3] = mask (causal, known analytically -> unused)
  const float* fc = (const float*)d_in[4];
  const float* fs = (const float*)d_in[5];
  const float* wq = (const float*)d_in[6];
  const float* bq = (const float*)d_in[7];
  const float* wk = (const float*)d_in[8];
  const float* bk = (const float*)d_in[9];
  const float* wv = (const float*)d_in[10];
  const float* bv = (const float*)d_in[11];
  const float* wo = (const float*)d_in[12];
  const float* bo = (const float*)d_in[13];
  float* out = (float*)d_out;
  bf16* ws = (bf16*)d_ws;

  const size_t MB_ = 1024 * 1024;  // elements
  bf16* Qbf  = ws;                     // 3 x 4M elems (Q,K,V bf16)
  bf16* Wqkv = ws + 12 * MB_;          // 3 x 1M (wq, wk, wv)
  bf16* Wo   = ws + 15 * MB_;          // 1M
  bf16* qp   = ws + 16 * MB_;          // q' [BH,S,HD] 4M
  bf16* kp   = ws + 20 * MB_;          // k' 4M
  bf16* vp   = ws + 24 * MB_;          // v' 4M
  bf16* vtp  = ws + 28 * MB_;          // v transposed [BH,HD,S] 4M
  bf16* aout = ws + 32 * MB_;          // attention output [M, D] 4M

  cvt_bf16<<<4096, 256, 0, stream>>>(Q, Qbf, 1048576);
  cvt_bf16<<<4096, 256, 0, stream>>>(K, Qbf + 4 * MB_, 1048576);
  cvt_bf16<<<4096, 256, 0, stream>>>(V, Qbf + 8 * MB_, 1048576);
  cvt_bf16<<<1024, 256, 0, stream>>>(wq, Wqkv, 262144);
  cvt_bf16<<<1024, 256, 0, stream>>>(wk, Wqkv + 1 * MB_, 262144);
  cvt_bf16<<<1024, 256, 0, stream>>>(wv, Wqkv + 2 * MB_, 262144);
  cvt_bf16<<<1024, 256, 0, stream>>>(wo, Wo, 262144);

  gemm_nt<0><<<dim3(8, 32, 3), 256, 0, stream>>>(Qbf, Wqkv, bq, bk, bv, qp, nullptr);

  rope_k<true ><<<8192, 256, 0, stream>>>(qp, fc, fs);
  rope_k<false><<<8192, 256, 0, stream>>>(kp, fc, fs);

  transpose_v<<<dim3(32, 32), 256, 0, stream>>>(vp, vtp);

  attn_k<<<dim3(16, 32), 256, 0, stream>>>(qp, kp, vtp, aout);

  gemm_nt<1><<<dim3(8, 32, 1), 256, 0, stream>>>(aout, Wo, bo, bo, bo, nullptr, out);
}

// Round 3
// 196.128 us; speedup vs baseline: 1.0388x; 1.0388x over previous
//
#include <hip/hip_runtime.h>
#include <stdint.h>

#define NB 2
#define NS 2048
#define ND 1024
#define NH 16
#define NHD 64
#define NM (NB*NS)   // 4096

typedef __bf16 bf16;
typedef float f32x4 __attribute__((ext_vector_type(4)));
typedef __bf16 bf16x8 __attribute__((ext_vector_type(8)));
typedef __bf16 bf16x4 __attribute__((ext_vector_type(4)));

#define MFMA16(a,b,c) __builtin_amdgcn_mfma_f32_16x16x32_bf16(a,b,c,0,0,0)

__device__ __forceinline__ void gld_lds16(const bf16* g, bf16* l) {
  __builtin_amdgcn_global_load_lds((const __attribute__((address_space(1))) void*)g,
                                   (__attribute__((address_space(3))) void*)l,
                                   16, 0, 0);
}

// ---------------- fp32 -> bf16 conversion, 3 equal tensors (Q,K,V) -------
__global__ __launch_bounds__(256)
void cvt3(const float* __restrict__ s0, const float* __restrict__ s1,
          const float* __restrict__ s2, bf16* __restrict__ dst, int n4each) {
  const int t = blockIdx.y;
  const float* s = (t == 0) ? s0 : (t == 1) ? s1 : s2;
  int i = blockIdx.x * blockDim.x + threadIdx.x;
  if (i >= n4each) return;
  float4 v = ((const float4*)s)[i];
  bf16x4 o = { (bf16)v.x, (bf16)v.y, (bf16)v.z, (bf16)v.w };
  ((bf16x4*)(dst + (size_t)t * n4each * 4))[i] = o;
}

// ---------------- fp32 -> bf16 conversion, 4 weight matrices --------------
__global__ __launch_bounds__(256)
void cvt_w4(const float* __restrict__ s0, const float* __restrict__ s1,
            const float* __restrict__ s2, const float* __restrict__ s3,
            bf16* __restrict__ dst, int n4each) {
  const int t = blockIdx.y;
  const float* s = (t == 0) ? s0 : (t == 1) ? s1 : (t == 2) ? s2 : s3;
  int i = blockIdx.x * blockDim.x + threadIdx.x;
  if (i >= n4each) return;
  float4 v = ((const float4*)s)[i];
  bf16x4 o = { (bf16)v.x, (bf16)v.y, (bf16)v.z, (bf16)v.w };
  ((bf16x4*)(dst + (size_t)t * n4each * 4))[i] = o;
}

// ---------------- NT GEMM: C[m,n] = sum_k A[m,k]*W[n,k] + bias[n] --------
// MODE 0: QKV projection; fused RoPE (t<2) + 1/sqrt(HD) scale (t==0);
//         bf16 out scattered to [B,H,S,HD] (z = tensor 0..2)
// MODE 1: output projection, fp32 out row-major [M, D]
template<int MODE>
__global__ __launch_bounds__(256)
void gemm_nt(const bf16* __restrict__ A, const bf16* __restrict__ W,
             const float* __restrict__ b0, const float* __restrict__ b1,
             const float* __restrict__ b2,
             const float* __restrict__ fc, const float* __restrict__ fs,
             bf16* __restrict__ obf, float* __restrict__ of) {
  constexpr int K = ND;
  __shared__ __align__(16) bf16 As[128 * 32];
  __shared__ __align__(16) bf16 Bs[128 * 32];
  const int tid = threadIdx.x;
  const int w = tid >> 6, lane = tid & 63;
  const int nt = blockIdx.x, mt = blockIdx.y, t = blockIdx.z;
  const bf16* Ab = A + (size_t)t * ((size_t)NM * K);
  const bf16* Wb = W + (size_t)t * ((size_t)ND * K);
  const float* bias = (t == 0) ? b0 : (t == 1) ? b1 : b2;
  const int wr = (w >> 1) * 64, wc = (w & 1) * 64;
  f32x4 acc[4][4] = {};
  const bf16* ga = Ab + (size_t)(mt * 128 + (tid >> 2)) * K + (tid & 3) * 8;
  const bf16* gb = Wb + (size_t)(nt * 128 + (tid >> 2)) * K + (tid & 3) * 8;
  bf16* lA = As + w * 512;   // wave-uniform LDS base (gld_lds writes base + lane*16)
  bf16* lB = Bs + w * 512;
  for (int k0 = 0; k0 < K; k0 += 32) {
    __syncthreads();
    gld_lds16(ga + k0, lA);
    gld_lds16(ga + (size_t)64 * K + k0, lA + 64 * 32);
    gld_lds16(gb + k0, lB);
    gld_lds16(gb + (size_t)64 * K + k0, lB + 64 * 32);
    __syncthreads();   // compiler drains vmcnt(0) before s_barrier -> LDS ready
    bf16x8 af[4], bfr[4];
#pragma unroll
    for (int i = 0; i < 4; ++i) {
      af[i]  = *(const bf16x8*)&As[(wr + i * 16 + (lane & 15)) * 32 + (lane >> 4) * 8];
      bfr[i] = *(const bf16x8*)&Bs[(wc + i * 16 + (lane & 15)) * 32 + (lane >> 4) * 8];
    }
#pragma unroll
    for (int i = 0; i < 4; ++i)
#pragma unroll
      for (int j = 0; j < 4; ++j)
        acc[i][j] = MFMA16(af[i], bfr[j], acc[i][j]);
  }
#pragma unroll
  for (int i = 0; i < 4; ++i) {
#pragma unroll
    for (int j = 0; j < 4; ++j) {
      const int gcol = nt * 128 + wc + j * 16 + (lane & 15);
      const float bv = bias[gcol];
#pragma unroll
      for (int r = 0; r < 4; ++r) {
        const int grow = mt * 128 + wr + i * 16 + (lane >> 4) * 4 + r;
        float v = acc[i][j][r] + bv;
        if (MODE == 0) {
          const int b = grow >> 11, s = grow & (NS - 1);
          const int h = gcol >> 6, hd = gcol & 63;
          if (t < 2) {   // fused RoPE: lane pairs hold adjacent hd columns
            float pv = __shfl_xor(v, 1);
            const int ii = hd >> 1;
            float c  = fc[(s << 5) + ii];
            float sn = fs[(s << 5) + ii];
            // even hd: out_r = xr*c - xi*s   (v=xr, pv=xi)
            // odd  hd: out_i = xr*s + xi*c   (v=xi, pv=xr)
            v = ((hd & 1) == 0) ? (v * c - pv * sn) : (pv * sn + v * c);
            if (t == 0) v *= 0.125f;   // fold 1/sqrt(HD)
          }
          obf[(size_t)t * ((size_t)NM * ND) +
              (((size_t)(b * NH + h) * NS + s) * NHD + hd)] = (bf16)v;
        } else {
          of[(size_t)grow * ND + gcol] = v;
        }
      }
    }
  }
}

// ---------------- V transpose: [BH, S, 64] -> [BH, 64, S] ----------------
__global__ __launch_bounds__(256)
void transpose_v(const bf16* __restrict__ v, bf16* __restrict__ vt) {
  __shared__ __align__(16) bf16 t[64][72];
  const int s0 = blockIdx.x * 64;
  const int bh = blockIdx.y;
  const bf16* src = v + ((size_t)bh * NS + s0) * NHD;
#pragma unroll
  for (int it = 0; it < 2; ++it) {
    int slot = threadIdx.x + it * 256;
    int r = slot >> 3, c8 = (slot & 7) * 8;
    *(bf16x8*)&t[r][c8] = *(const bf16x8*)&src[(size_t)r * NHD + c8];
  }
  __syncthreads();
  bf16* dst = vt + (size_t)bh * NHD * NS + s0;
#pragma unroll
  for (int it = 0; it < 2; ++it) {
    int slot = threadIdx.x + it * 256;
    int r = slot >> 3, c8 = (slot & 7) * 8;   // r = hd row of output, c8 = s offset
    bf16x8 vv;
#pragma unroll
    for (int e = 0; e < 8; ++e) vv[e] = t[c8 + e][r];
    *(bf16x8*)&dst[(size_t)r * NS + c8] = vv;
  }
}

// ---------------- flash attention, causal, 4 waves x 16 q-rows -----------
// grid (32, 32): x -> paired q-tile (balance), y -> bh
__global__ __launch_bounds__(256)
void attn_k(const bf16* __restrict__ q, const bf16* __restrict__ k,
            const bf16* __restrict__ vt, bf16* __restrict__ out) {
  __shared__ __align__(16) bf16 Ks[64][72];       // [k-pos][hd], padded
  __shared__ __align__(16) bf16 Vs[64][72];       // [hd][k-pos], padded
  __shared__ __align__(16) bf16 P[4][16][72];     // per-wave P tile
  const int w = threadIdx.x >> 6, lane = threadIdx.x & 63;
  const int x = blockIdx.x;
  const int qt = (x & 1) ? (31 - (x >> 1)) : (x >> 1);   // pair (qt, 31-qt): const work
  const int bh = blockIdx.y;
  const int b = bh >> 4, h = bh & (NH - 1);
  const int q0 = qt * 64 + w * 16;

  const bf16* qb = q + ((size_t)bh * NS + q0) * NHD;
  bf16x8 qf[2];
#pragma unroll
  for (int ch = 0; ch < 2; ++ch)
    qf[ch] = *(const bf16x8*)&qb[(size_t)(lane & 15) * NHD + ch * 32 + (lane >> 4) * 8];

  f32x4 o[4] = {};
  float mrow[4], lrow[4];
#pragma unroll
  for (int r = 0; r < 4; ++r) { mrow[r] = -1e30f; lrow[r] = 0.f; }

  const bf16* kb = k + (size_t)bh * NS * NHD;
  const bf16* vb = vt + (size_t)bh * NHD * NS;
  const int ktiles = qt + 1;

  for (int kt = 0; kt < ktiles; ++kt) {
    const int kk0 = kt * 64;
    __syncthreads();
#pragma unroll
    for (int it = 0; it < 2; ++it) {
      int slot = threadIdx.x + it * 256;
      int r = slot >> 3, c8 = (slot & 7) * 8;
      *(bf16x8*)&Ks[r][c8] = *(const bf16x8*)&kb[(size_t)(kk0 + r) * NHD + c8];
      *(bf16x8*)&Vs[r][c8] = *(const bf16x8*)&vb[(size_t)r * NS + kk0 + c8];
    }
    __syncthreads();

    const f32x4 vzero = {0.f, 0.f, 0.f, 0.f};
    f32x4 sc[4];
#pragma unroll
    for (int cb = 0; cb < 4; ++cb) sc[cb] = vzero;

    __builtin_amdgcn_s_setprio(1);
#pragma unroll
    for (int ch = 0; ch < 2; ++ch) {
#pragma unroll
      for (int cb = 0; cb < 4; ++cb) {
        bf16x8 kf = *(const bf16x8*)&Ks[cb * 16 + (lane & 15)][ch * 32 + (lane >> 4) * 8];
        sc[cb] = MFMA16(qf[ch], kf, sc[cb]);
      }
    }
    __builtin_amdgcn_s_setprio(0);

    if (kk0 + 63 > q0) {   // diagonal tile for this wave -> elementwise causal mask
#pragma unroll
      for (int cb = 0; cb < 4; ++cb)
#pragma unroll
        for (int r = 0; r < 4; ++r) {
          int qi = q0 + (lane >> 4) * 4 + r;
          int kj = kk0 + cb * 16 + (lane & 15);
          if (kj > qi) sc[cb][r] = -1e30f;
        }
    }

    float tm[4];
#pragma unroll
    for (int r = 0; r < 4; ++r)
      tm[r] = fmaxf(fmaxf(sc[0][r], sc[1][r]), fmaxf(sc[2][r], sc[3][r]));
#pragma unroll
    for (int off = 1; off < 16; off <<= 1)
#pragma unroll
      for (int r = 0; r < 4; ++r)
        tm[r] = fmaxf(tm[r], __shfl_xor(tm[r], off));
#pragma unroll
    for (int r = 0; r < 4; ++r) {
      float mn = fmaxf(mrow[r], tm[r]);
      float scl = __expf(mrow[r] - mn);
      mrow[r] = mn;
      lrow[r] *= scl;
#pragma unroll
      for (int hb = 0; hb < 4; ++hb) o[hb][r] *= scl;
      float ps = 0.f;
#pragma unroll
      for (int cb = 0; cb < 4; ++cb) {
        float p = __expf(sc[cb][r] - mn);
        ps += p;
        P[w][(lane >> 4) * 4 + r][cb * 16 + (lane & 15)] = (bf16)p;
      }
      lrow[r] += ps;   // per-lane partial; reduced across 16 lanes at the end
    }

    __builtin_amdgcn_s_setprio(1);
#pragma unroll
    for (int ch = 0; ch < 2; ++ch) {
      bf16x8 pa = *(const bf16x8*)&P[w][(lane & 15)][ch * 32 + (lane >> 4) * 8];
#pragma unroll
      for (int hb = 0; hb < 4; ++hb) {
        bf16x8 vf = *(const bf16x8*)&Vs[hb * 16 + (lane & 15)][ch * 32 + (lane >> 4) * 8];
        o[hb] = MFMA16(pa, vf, o[hb]);
      }
    }
    __builtin_amdgcn_s_setprio(0);
  }

  float ls[4];
#pragma unroll
  for (int r = 0; r < 4; ++r) ls[r] = lrow[r];
#pragma unroll
  for (int off = 1; off < 16; off <<= 1)
#pragma unroll
    for (int r = 0; r < 4; ++r) ls[r] += __shfl_xor(ls[r], off);
#pragma unroll
  for (int r = 0; r < 4; ++r) {
    float inv = 1.f / ls[r];
    int s = q0 + (lane >> 4) * 4 + r;
#pragma unroll
    for (int hb = 0; hb < 4; ++hb) {
      int gcol = h * NHD + hb * 16 + (lane & 15);
      out[(size_t)(b * NS + s) * ND + gcol] = (bf16)(o[hb][r] * inv);
    }
  }
}

// -------------------------------------------------------------------------
extern "C" void kernel_launch(void* const* d_in, const int* in_sizes, int n_in,
                              void* d_out, int out_size, void* d_ws, size_t ws_size,
                              hipStream_t stream) {
  const float* Q  = (const float*)d_in[0];
  const float* K  = (const float*)d_in[1];
  const float* V  = (const float*)d_in[2];
  // d_in[3] = mask (causal, known analytically -> unused)
  const float* fc = (const float*)d_in[4];
  const float* fs = (const float*)d_in[5];
  const float* wq = (const float*)d_in[6];
  const float* bq = (const float*)d_in[7];
  const float* wk = (const float*)d_in[8];
  const float* bk = (const float*)d_in[9];
  const float* wv = (const float*)d_in[10];
  const float* bv = (const float*)d_in[11];
  const float* wo = (const float*)d_in[12];
  const float* bo = (const float*)d_in[13];
  float* out = (float*)d_out;
  bf16* ws = (bf16*)d_ws;

  const size_t MB_ = 1024 * 1024;  // elements
  bf16* Qbf  = ws;                     // 3 x 4M elems (Q,K,V bf16)
  bf16* Wqkv = ws + 12 * MB_;          // 3 x 1M (wq, wk, wv)  [wo follows at +15M]
  bf16* Wo   = ws + 15 * MB_;
  bf16* qp   = ws + 16 * MB_;          // q' [BH,S,HD] 4M
  bf16* kp   = ws + 20 * MB_;          // k' 4M
  bf16* vp   = ws + 24 * MB_;          // v' 4M
  bf16* vtp  = ws + 28 * MB_;          // v transposed [BH,HD,S] 4M
  bf16* aout = ws + 32 * MB_;          // attention output [M, D] 4M

  cvt3<<<dim3(4096, 3), 256, 0, stream>>>(Q, K, V, Qbf, 1048576);
  cvt_w4<<<dim3(1024, 4), 256, 0, stream>>>(wq, wk, wv, wo, Wqkv, 262144);

  gemm_nt<0><<<dim3(8, 32, 3), 256, 0, stream>>>(Qbf, Wqkv, bq, bk, bv, fc, fs, qp, nullptr);

  transpose_v<<<dim3(32, 32), 256, 0, stream>>>(vp, vtp);

  attn_k<<<dim3(32, 32), 256, 0, stream>>>(qp, kp, vtp, aout);

  gemm_nt<1><<<dim3(8, 32, 1), 256, 0, stream>>>(aout, Wo, bo, bo, bo, fc, fs, nullptr, out);
}

// Round 4
// 175.778 us; speedup vs baseline: 1.1591x; 1.1158x over previous
//
#include <hip/hip_runtime.h>
#include <stdint.h>

#define NB 2
#define NS 2048
#define ND 1024
#define NH 16
#define NHD 64
#define NM (NB*NS)   // 4096

typedef __bf16 bf16;
typedef float f32x4 __attribute__((ext_vector_type(4)));
typedef __bf16 bf16x8 __attribute__((ext_vector_type(8)));
typedef __bf16 bf16x4 __attribute__((ext_vector_type(4)));

#define MFMA16(a,b,c) __builtin_amdgcn_mfma_f32_16x16x32_bf16(a,b,c,0,0,0)

__device__ __forceinline__ void gld_lds16(const bf16* g, bf16* l) {
  __builtin_amdgcn_global_load_lds((const __attribute__((address_space(1))) void*)g,
                                   (__attribute__((address_space(3))) void*)l,
                                   16, 0, 0);
}

// Barrier that drains LDS ops but leaves global loads in flight (vmcnt
// untouched) — unlike __syncthreads(), which drains vmcnt(0) and would
// serialize the staging pipeline. CK's block_sync_lds pattern.
__device__ __forceinline__ void block_sync_lds() {
  asm volatile("s_waitcnt lgkmcnt(0)\n\ts_barrier" ::: "memory");
}

// ---------------- fp32 -> bf16 conversion, 3 equal tensors (Q,K,V) -------
__global__ __launch_bounds__(256)
void cvt3(const float* __restrict__ s0, const float* __restrict__ s1,
          const float* __restrict__ s2, bf16* __restrict__ dst, int n4each) {
  const int t = blockIdx.y;
  const float* s = (t == 0) ? s0 : (t == 1) ? s1 : s2;
  int i = blockIdx.x * blockDim.x + threadIdx.x;
  if (i >= n4each) return;
  float4 v = ((const float4*)s)[i];
  bf16x4 o = { (bf16)v.x, (bf16)v.y, (bf16)v.z, (bf16)v.w };
  ((bf16x4*)(dst + (size_t)t * n4each * 4))[i] = o;
}

// ---------------- fp32 -> bf16 conversion, 4 weight matrices --------------
__global__ __launch_bounds__(256)
void cvt_w4(const float* __restrict__ s0, const float* __restrict__ s1,
            const float* __restrict__ s2, const float* __restrict__ s3,
            bf16* __restrict__ dst, int n4each) {
  const int t = blockIdx.y;
  const float* s = (t == 0) ? s0 : (t == 1) ? s1 : (t == 2) ? s2 : s3;
  int i = blockIdx.x * blockDim.x + threadIdx.x;
  if (i >= n4each) return;
  float4 v = ((const float4*)s)[i];
  bf16x4 o = { (bf16)v.x, (bf16)v.y, (bf16)v.z, (bf16)v.w };
  ((bf16x4*)(dst + (size_t)t * n4each * 4))[i] = o;
}

// ---------------- NT GEMM: C[m,n] = sum_k A[m,k]*W[n,k] + bias[n] --------
// MODE 0: QKV projection; fused RoPE (t<2) + 1/sqrt(HD) scale (t==0);
//         bf16 out scattered to [B,H,S,HD] (z = tensor 0..2)
// MODE 1: output projection, fp32 out row-major [M, D]
template<int MODE>
__global__ __launch_bounds__(256)
void gemm_nt(const bf16* __restrict__ A, const bf16* __restrict__ W,
             const float* __restrict__ b0, const float* __restrict__ b1,
             const float* __restrict__ b2,
             const float* __restrict__ fc, const float* __restrict__ fs,
             bf16* __restrict__ obf, float* __restrict__ of) {
  constexpr int K = ND;
  __shared__ __align__(16) bf16 As[128 * 32];
  __shared__ __align__(16) bf16 Bs[128 * 32];
  const int tid = threadIdx.x;
  const int w = tid >> 6, lane = tid & 63;
  const int nt = blockIdx.x, mt = blockIdx.y, t = blockIdx.z;
  const bf16* Ab = A + (size_t)t * ((size_t)NM * K);
  const bf16* Wb = W + (size_t)t * ((size_t)ND * K);
  const float* bias = (t == 0) ? b0 : (t == 1) ? b1 : b2;
  const int wr = (w >> 1) * 64, wc = (w & 1) * 64;
  f32x4 acc[4][4] = {};
  const bf16* ga = Ab + (size_t)(mt * 128 + (tid >> 2)) * K + (tid & 3) * 8;
  const bf16* gb = Wb + (size_t)(nt * 128 + (tid >> 2)) * K + (tid & 3) * 8;
  bf16* lA = As + w * 512;   // wave-uniform LDS base (gld_lds writes base + lane*16)
  bf16* lB = Bs + w * 512;
  for (int k0 = 0; k0 < K; k0 += 32) {
    __syncthreads();
    gld_lds16(ga + k0, lA);
    gld_lds16(ga + (size_t)64 * K + k0, lA + 64 * 32);
    gld_lds16(gb + k0, lB);
    gld_lds16(gb + (size_t)64 * K + k0, lB + 64 * 32);
    __syncthreads();   // compiler drains vmcnt(0) before s_barrier -> LDS ready
    bf16x8 af[4], bfr[4];
#pragma unroll
    for (int i = 0; i < 4; ++i) {
      af[i]  = *(const bf16x8*)&As[(wr + i * 16 + (lane & 15)) * 32 + (lane >> 4) * 8];
      bfr[i] = *(const bf16x8*)&Bs[(wc + i * 16 + (lane & 15)) * 32 + (lane >> 4) * 8];
    }
#pragma unroll
    for (int i = 0; i < 4; ++i)
#pragma unroll
      for (int j = 0; j < 4; ++j)
        acc[i][j] = MFMA16(af[i], bfr[j], acc[i][j]);
  }
#pragma unroll
  for (int i = 0; i < 4; ++i) {
#pragma unroll
    for (int j = 0; j < 4; ++j) {
      const int gcol = nt * 128 + wc + j * 16 + (lane & 15);
      const float bv = bias[gcol];
#pragma unroll
      for (int r = 0; r < 4; ++r) {
        const int grow = mt * 128 + wr + i * 16 + (lane >> 4) * 4 + r;
        float v = acc[i][j][r] + bv;
        if (MODE == 0) {
          const int b = grow >> 11, s = grow & (NS - 1);
          const int h = gcol >> 6, hd = gcol & 63;
          if (t < 2) {   // fused RoPE: lane pairs hold adjacent hd columns
            float pv = __shfl_xor(v, 1);
            const int ii = hd >> 1;
            float c  = fc[(s << 5) + ii];
            float sn = fs[(s << 5) + ii];
            // even hd: out_r = xr*c - xi*s   (v=xr, pv=xi)
            // odd  hd: out_i = xr*s + xi*c   (v=xi, pv=xr)
            v = ((hd & 1) == 0) ? (v * c - pv * sn) : (pv * sn + v * c);
            if (t == 0) v *= 0.125f;   // fold 1/sqrt(HD)
          }
          obf[(size_t)t * ((size_t)NM * ND) +
              (((size_t)(b * NH + h) * NS + s) * NHD + hd)] = (bf16)v;
        } else {
          of[(size_t)grow * ND + gcol] = v;
        }
      }
    }
  }
}

// ---------------- V transpose: [BH, S, 64] -> [BH, 64, S] ----------------
__global__ __launch_bounds__(256)
void transpose_v(const bf16* __restrict__ v, bf16* __restrict__ vt) {
  __shared__ __align__(16) bf16 t[64][72];
  const int s0 = blockIdx.x * 64;
  const int bh = blockIdx.y;
  const bf16* src = v + ((size_t)bh * NS + s0) * NHD;
#pragma unroll
  for (int it = 0; it < 2; ++it) {
    int slot = threadIdx.x + it * 256;
    int r = slot >> 3, c8 = (slot & 7) * 8;
    *(bf16x8*)&t[r][c8] = *(const bf16x8*)&src[(size_t)r * NHD + c8];
  }
  __syncthreads();
  bf16* dst = vt + (size_t)bh * NHD * NS + s0;
#pragma unroll
  for (int it = 0; it < 2; ++it) {
    int slot = threadIdx.x + it * 256;
    int r = slot >> 3, c8 = (slot & 7) * 8;   // r = hd row of output, c8 = s offset
    bf16x8 vv;
#pragma unroll
    for (int e = 0; e < 8; ++e) vv[e] = t[c8 + e][r];
    *(bf16x8*)&dst[(size_t)r * NS + c8] = vv;
  }
}

// ---------------- flash attention, causal, 4 waves x 16 q-rows -----------
// Swapped-operand form: QK^T computed as S^T = mfma(K,Q)  (lane&15 = q row),
// PV computed as O^T = mfma(V^T, P)  (lane&15 = q row) -> softmax state is
// per-lane scalar, P stores are packed b64, reductions are 2 shfl rounds.
// K/V staging is double-buffered: global->reg issued before the barrier
// (vmcnt survives block_sync_lds), reg->LDS written after compute.
// grid (32, 32): x -> paired q-tile (balance), y -> bh
__global__ __launch_bounds__(256)
void attn_k(const bf16* __restrict__ q, const bf16* __restrict__ k,
            const bf16* __restrict__ vt, bf16* __restrict__ out) {
  __shared__ __align__(16) bf16 Ks[2][64][72];    // [buf][k-pos][hd]
  __shared__ __align__(16) bf16 Vs[2][64][72];    // [buf][hd][k-pos]
  __shared__ __align__(16) bf16 P[4][16][72];     // [wave][q-row][k]
  const int w = threadIdx.x >> 6, lane = threadIdx.x & 63;
  const int x = blockIdx.x;
  const int qt = (x & 1) ? (31 - (x >> 1)) : (x >> 1);   // pair (qt, 31-qt): const work
  const int bh = blockIdx.y;
  const int b = bh >> 4, h = bh & (NH - 1);
  const int q0 = qt * 64 + w * 16;
  const int qrow = lane & 15, grp = lane >> 4;

  const bf16* qb = q + ((size_t)bh * NS + q0) * NHD;
  bf16x8 qf[2];
#pragma unroll
  for (int ch = 0; ch < 2; ++ch)
    qf[ch] = *(const bf16x8*)&qb[(size_t)qrow * NHD + ch * 32 + grp * 8];

  f32x4 o[4] = {};
  float mrow = -1e30f, lrow = 0.f;

  const bf16* kb = k + (size_t)bh * NS * NHD;
  const bf16* vb = vt + (size_t)bh * NHD * NS;
  const int ktiles = qt + 1;

  const int sr  = threadIdx.x >> 3;         // staging row 0..31 (and +32)
  const int sc8 = (threadIdx.x & 7) * 8;    // staging col (x8 bf16)

  // prologue: stage tile 0
  {
    bf16x8 a = *(const bf16x8*)&kb[(size_t)sr * NHD + sc8];
    bf16x8 c = *(const bf16x8*)&kb[(size_t)(sr + 32) * NHD + sc8];
    bf16x8 d = *(const bf16x8*)&vb[(size_t)sr * NS + sc8];
    bf16x8 e = *(const bf16x8*)&vb[(size_t)(sr + 32) * NS + sc8];
    *(bf16x8*)&Ks[0][sr][sc8] = a;  *(bf16x8*)&Ks[0][sr + 32][sc8] = c;
    *(bf16x8*)&Vs[0][sr][sc8] = d;  *(bf16x8*)&Vs[0][sr + 32][sc8] = e;
  }

  bf16x8 kr0, kr1, vr0, vr1;
  for (int kt = 0; kt < ktiles; ++kt) {
    const int cur = kt & 1;
    const bool pre = (kt + 1 < ktiles);
    if (pre) {   // issue next-tile loads; latency hides under barrier+compute
      const int kn = (kt + 1) * 64;
      kr0 = *(const bf16x8*)&kb[(size_t)(kn + sr) * NHD + sc8];
      kr1 = *(const bf16x8*)&kb[(size_t)(kn + sr + 32) * NHD + sc8];
      vr0 = *(const bf16x8*)&vb[(size_t)sr * NS + kn + sc8];
      vr1 = *(const bf16x8*)&vb[(size_t)(sr + 32) * NS + kn + sc8];
    }
    block_sync_lds();   // publishes buf[cur]; in-flight global loads survive

    f32x4 sc[4] = {};
    __builtin_amdgcn_s_setprio(1);
#pragma unroll
    for (int ch = 0; ch < 2; ++ch) {
#pragma unroll
      for (int cb = 0; cb < 4; ++cb) {
        bf16x8 kf = *(const bf16x8*)&Ks[cur][cb * 16 + qrow][ch * 32 + grp * 8];
        sc[cb] = MFMA16(kf, qf[ch], sc[cb]);   // S^T[k][q]
      }
    }
    __builtin_amdgcn_s_setprio(0);

    if (kt == ktiles - 1) {   // only the last tile crosses the diagonal
      const int kk0 = kt * 64, qi = q0 + qrow;
#pragma unroll
      for (int cb = 0; cb < 4; ++cb)
#pragma unroll
        for (int r = 0; r < 4; ++r)
          if (kk0 + cb * 16 + grp * 4 + r > qi) sc[cb][r] = -1e30f;
    }

    // online softmax; lane owns q-row (lane&15); 16 S values per lane
    float pm = sc[0][0];
#pragma unroll
    for (int cb = 0; cb < 4; ++cb)
#pragma unroll
      for (int r = 0; r < 4; ++r) pm = fmaxf(pm, sc[cb][r]);
    pm = fmaxf(pm, __shfl_xor(pm, 16));
    pm = fmaxf(pm, __shfl_xor(pm, 32));
    const float mn = fmaxf(mrow, pm);
    const float scl = __expf(mrow - mn);
    mrow = mn;
    lrow *= scl;
#pragma unroll
    for (int cb = 0; cb < 4; ++cb) {
      bf16x4 pk;
#pragma unroll
      for (int r = 0; r < 4; ++r) {
        float p = __expf(sc[cb][r] - mn);
        lrow += p;
        pk[r] = (bf16)p;
      }
      *(bf16x4*)&P[w][qrow][cb * 16 + grp * 4] = pk;   // packed b64 store
    }
#pragma unroll
    for (int hb = 0; hb < 4; ++hb)
#pragma unroll
      for (int r = 0; r < 4; ++r) o[hb][r] *= scl;

    __builtin_amdgcn_s_setprio(1);
#pragma unroll
    for (int ch = 0; ch < 2; ++ch) {
      bf16x8 pa = *(const bf16x8*)&P[w][qrow][ch * 32 + grp * 8];   // B-operand
#pragma unroll
      for (int hb = 0; hb < 4; ++hb) {
        bf16x8 vf = *(const bf16x8*)&Vs[cur][hb * 16 + qrow][ch * 32 + grp * 8];
        o[hb] = MFMA16(vf, pa, o[hb]);   // O^T[hd][q]
      }
    }
    __builtin_amdgcn_s_setprio(0);

    if (pre) {   // write next tile into the other buffer (published next iter)
      *(bf16x8*)&Ks[cur ^ 1][sr][sc8] = kr0;
      *(bf16x8*)&Ks[cur ^ 1][sr + 32][sc8] = kr1;
      *(bf16x8*)&Vs[cur ^ 1][sr][sc8] = vr0;
      *(bf16x8*)&Vs[cur ^ 1][sr + 32][sc8] = vr1;
    }
  }

  lrow += __shfl_xor(lrow, 16);
  lrow += __shfl_xor(lrow, 32);
  const float inv = 1.f / lrow;
  const int s = q0 + qrow;
  bf16* op = out + (size_t)(b * NS + s) * ND + h * NHD + grp * 4;
#pragma unroll
  for (int hb = 0; hb < 4; ++hb) {
    bf16x4 ov = { (bf16)(o[hb][0] * inv), (bf16)(o[hb][1] * inv),
                  (bf16)(o[hb][2] * inv), (bf16)(o[hb][3] * inv) };
    *(bf16x4*)&op[hb * 16] = ov;
  }
}

// -------------------------------------------------------------------------
extern "C" void kernel_launch(void* const* d_in, const int* in_sizes, int n_in,
                              void* d_out, int out_size, void* d_ws, size_t ws_size,
                              hipStream_t stream) {
  const float* Q  = (const float*)d_in[0];
  const float* K  = (const float*)d_in[1];
  const float* V  = (const float*)d_in[2];
  // d_in[3] = mask (causal, known analytically -> unused)
  const float* fc = (const float*)d_in[4];
  const float* fs = (const float*)d_in[5];
  const float* wq = (const float*)d_in[6];
  const float* bq = (const float*)d_in[7];
  const float* wk = (const float*)d_in[8];
  const float* bk = (const float*)d_in[9];
  const float* wv = (const float*)d_in[10];
  const float* bv = (const float*)d_in[11];
  const float* wo = (const float*)d_in[12];
  const float* bo = (const float*)d_in[13];
  float* out = (float*)d_out;
  bf16* ws = (bf16*)d_ws;

  const size_t MB_ = 1024 * 1024;  // elements
  bf16* Qbf  = ws;                     // 3 x 4M elems (Q,K,V bf16)
  bf16* Wqkv = ws + 12 * MB_;          // 3 x 1M (wq, wk, wv)
  bf16* Wo   = ws + 15 * MB_;          // 1M
  bf16* qp   = ws + 16 * MB_;          // q' [BH,S,HD] 4M
  bf16* kp   = ws + 20 * MB_;          // k' 4M
  bf16* vp   = ws + 24 * MB_;          // v' 4M
  bf16* vtp  = ws + 28 * MB_;          // v transposed [BH,HD,S] 4M
  bf16* aout = ws + 32 * MB_;          // attention output [M, D] 4M

  cvt3<<<dim3(4096, 3), 256, 0, stream>>>(Q, K, V, Qbf, 1048576);
  cvt_w4<<<dim3(1024, 4), 256, 0, stream>>>(wq, wk, wv, wo, Wqkv, 262144);

  gemm_nt<0><<<dim3(8, 32, 3), 256, 0, stream>>>(Qbf, Wqkv, bq, bk, bv, fc, fs, qp, nullptr);

  transpose_v<<<dim3(32, 32), 256, 0, stream>>>(vp, vtp);

  attn_k<<<dim3(32, 32), 256, 0, stream>>>(qp, kp, vtp, aout);

  gemm_nt<1><<<dim3(8, 32, 1), 256, 0, stream>>>(aout, Wo, bo, bo, bo, fc, fs, nullptr, out);
}

// Round 5
// 165.370 us; speedup vs baseline: 1.2321x; 1.0629x over previous
//
#include <hip/hip_runtime.h>
#include <stdint.h>

#define NB 2
#define NS 2048
#define ND 1024
#define NH 16
#define NHD 64
#define NM (NB*NS)   // 4096

typedef __bf16 bf16;
typedef float f32x4 __attribute__((ext_vector_type(4)));
typedef __bf16 bf16x8 __attribute__((ext_vector_type(8)));
typedef __bf16 bf16x4 __attribute__((ext_vector_type(4)));

#define MFMA16(a,b,c) __builtin_amdgcn_mfma_f32_16x16x32_bf16(a,b,c,0,0,0)

__device__ __forceinline__ void gld_lds16(const bf16* g, bf16* l) {
  __builtin_amdgcn_global_load_lds((const __attribute__((address_space(1))) void*)g,
                                   (__attribute__((address_space(3))) void*)l,
                                   16, 0, 0);
}

// Barrier that drains LDS ops but leaves global loads in flight (vmcnt
// untouched) — unlike __syncthreads(), which drains vmcnt(0).
__device__ __forceinline__ void block_sync_lds() {
  asm volatile("s_waitcnt lgkmcnt(0)\n\ts_barrier" ::: "memory");
}

// ---------------- fp32 -> bf16 conversion, 3 equal tensors (Q,K,V) -------
__global__ __launch_bounds__(256)
void cvt3(const float* __restrict__ s0, const float* __restrict__ s1,
          const float* __restrict__ s2, bf16* __restrict__ dst, int n4each) {
  const int t = blockIdx.y;
  const float* s = (t == 0) ? s0 : (t == 1) ? s1 : s2;
  int i = blockIdx.x * blockDim.x + threadIdx.x;
  if (i >= n4each) return;
  float4 v = ((const float4*)s)[i];
  bf16x4 o = { (bf16)v.x, (bf16)v.y, (bf16)v.z, (bf16)v.w };
  ((bf16x4*)(dst + (size_t)t * n4each * 4))[i] = o;
}

// ---------------- fp32 -> bf16 conversion, 4 weight matrices --------------
__global__ __launch_bounds__(256)
void cvt_w4(const float* __restrict__ s0, const float* __restrict__ s1,
            const float* __restrict__ s2, const float* __restrict__ s3,
            bf16* __restrict__ dst, int n4each) {
  const int t = blockIdx.y;
  const float* s = (t == 0) ? s0 : (t == 1) ? s1 : (t == 2) ? s2 : s3;
  int i = blockIdx.x * blockDim.x + threadIdx.x;
  if (i >= n4each) return;
  float4 v = ((const float4*)s)[i];
  bf16x4 o = { (bf16)v.x, (bf16)v.y, (bf16)v.z, (bf16)v.w };
  ((bf16x4*)(dst + (size_t)t * n4each * 4))[i] = o;
}

// ---------------- NT GEMM: C[m,n] = sum_k A[m,k]*W[n,k] + bias[n] --------
// MODE 0: QKV projection; fused RoPE (t<2); q additionally scaled by
//         (1/sqrt(HD))*log2(e) so attention softmax can use exp2.
//         bf16 out scattered to [B,H,S,HD] (z = tensor 0..2)
// MODE 1: output projection, fp32 out row-major [M, D]
template<int MODE>
__global__ __launch_bounds__(256)
void gemm_nt(const bf16* __restrict__ A, const bf16* __restrict__ W,
             const float* __restrict__ b0, const float* __restrict__ b1,
             const float* __restrict__ b2,
             const float* __restrict__ fc, const float* __restrict__ fs,
             bf16* __restrict__ obf, float* __restrict__ of) {
  constexpr int K = ND;
  __shared__ __align__(16) bf16 As[128 * 32];
  __shared__ __align__(16) bf16 Bs[128 * 32];
  const int tid = threadIdx.x;
  const int w = tid >> 6, lane = tid & 63;
  const int nt = blockIdx.x, mt = blockIdx.y, t = blockIdx.z;
  const bf16* Ab = A + (size_t)t * ((size_t)NM * K);
  const bf16* Wb = W + (size_t)t * ((size_t)ND * K);
  const float* bias = (t == 0) ? b0 : (t == 1) ? b1 : b2;
  const int wr = (w >> 1) * 64, wc = (w & 1) * 64;
  f32x4 acc[4][4] = {};
  const bf16* ga = Ab + (size_t)(mt * 128 + (tid >> 2)) * K + (tid & 3) * 8;
  const bf16* gb = Wb + (size_t)(nt * 128 + (tid >> 2)) * K + (tid & 3) * 8;
  bf16* lA = As + w * 512;   // wave-uniform LDS base (gld_lds writes base + lane*16)
  bf16* lB = Bs + w * 512;
  for (int k0 = 0; k0 < K; k0 += 32) {
    __syncthreads();
    gld_lds16(ga + k0, lA);
    gld_lds16(ga + (size_t)64 * K + k0, lA + 64 * 32);
    gld_lds16(gb + k0, lB);
    gld_lds16(gb + (size_t)64 * K + k0, lB + 64 * 32);
    __syncthreads();   // compiler drains vmcnt(0) before s_barrier -> LDS ready
    bf16x8 af[4], bfr[4];
#pragma unroll
    for (int i = 0; i < 4; ++i) {
      af[i]  = *(const bf16x8*)&As[(wr + i * 16 + (lane & 15)) * 32 + (lane >> 4) * 8];
      bfr[i] = *(const bf16x8*)&Bs[(wc + i * 16 + (lane & 15)) * 32 + (lane >> 4) * 8];
    }
#pragma unroll
    for (int i = 0; i < 4; ++i)
#pragma unroll
      for (int j = 0; j < 4; ++j)
        acc[i][j] = MFMA16(af[i], bfr[j], acc[i][j]);
  }
#pragma unroll
  for (int i = 0; i < 4; ++i) {
#pragma unroll
    for (int j = 0; j < 4; ++j) {
      const int gcol = nt * 128 + wc + j * 16 + (lane & 15);
      const float bv = bias[gcol];
#pragma unroll
      for (int r = 0; r < 4; ++r) {
        const int grow = mt * 128 + wr + i * 16 + (lane >> 4) * 4 + r;
        float v = acc[i][j][r] + bv;
        if (MODE == 0) {
          const int b = grow >> 11, s = grow & (NS - 1);
          const int h = gcol >> 6, hd = gcol & 63;
          if (t < 2) {   // fused RoPE: lane pairs hold adjacent hd columns
            float pv = __shfl_xor(v, 1);
            const int ii = hd >> 1;
            float c  = fc[(s << 5) + ii];
            float sn = fs[(s << 5) + ii];
            // even hd: out_r = xr*c - xi*s   (v=xr, pv=xi)
            // odd  hd: out_i = xr*s + xi*c   (v=xi, pv=xr)
            v = ((hd & 1) == 0) ? (v * c - pv * sn) : (pv * sn + v * c);
            if (t == 0) v *= 0.18033688011112042f;   // (1/sqrt(HD)) * log2(e)
          }
          obf[(size_t)t * ((size_t)NM * ND) +
              (((size_t)(b * NH + h) * NS + s) * NHD + hd)] = (bf16)v;
        } else {
          of[(size_t)grow * ND + gcol] = v;
        }
      }
    }
  }
}

// ---------------- V transpose: [BH, S, 64] -> [BH, 64, S] ----------------
__global__ __launch_bounds__(256)
void transpose_v(const bf16* __restrict__ v, bf16* __restrict__ vt) {
  __shared__ __align__(16) bf16 t[64][72];
  const int s0 = blockIdx.x * 64;
  const int bh = blockIdx.y;
  const bf16* src = v + ((size_t)bh * NS + s0) * NHD;
#pragma unroll
  for (int it = 0; it < 2; ++it) {
    int slot = threadIdx.x + it * 256;
    int r = slot >> 3, c8 = (slot & 7) * 8;
    *(bf16x8*)&t[r][c8] = *(const bf16x8*)&src[(size_t)r * NHD + c8];
  }
  __syncthreads();
  bf16* dst = vt + (size_t)bh * NHD * NS + s0;
#pragma unroll
  for (int it = 0; it < 2; ++it) {
    int slot = threadIdx.x + it * 256;
    int r = slot >> 3, c8 = (slot & 7) * 8;   // r = hd row of output, c8 = s offset
    bf16x8 vv;
#pragma unroll
    for (int e = 0; e < 8; ++e) vv[e] = t[c8 + e][r];
    *(bf16x8*)&dst[(size_t)r * NS + c8] = vv;
  }
}

// ---------------- flash attention, causal, 4 waves ------------------------
// One block owns the q-tile PAIR (qtA=x, qtB=31-x): every block does exactly
// 33 q-tile*k-tile computes -> uniform duration; grid 512 = 2 blocks/CU, all
// co-resident. While kt<=qtA both q-tiles are active: 32 MFMA per barrier
// with shared K/V fragment loads. Swapped-operand MFMAs keep softmax state
// per-lane scalar; softmax in base-2 (log2e folded into q upstream).
__global__ __launch_bounds__(256)
void attn_k(const bf16* __restrict__ q, const bf16* __restrict__ k,
            const bf16* __restrict__ vt, bf16* __restrict__ out) {
  __shared__ __align__(16) bf16 Ks[2][64][72];    // [buf][k-pos][hd]
  __shared__ __align__(16) bf16 Vs[2][64][72];    // [buf][hd][k-pos]
  __shared__ __align__(16) bf16 P[4][2][16][72];  // [wave][B/A][q-row][k]
  const int w = threadIdx.x >> 6, lane = threadIdx.x & 63;
  const int x = blockIdx.x;                       // 0..15
  const int bh = blockIdx.y;
  const int b = bh >> 4, h = bh & (NH - 1);
  const int qtA = x, qtB = 31 - x;
  const int q0A = qtA * 64 + w * 16, q0B = qtB * 64 + w * 16;
  const int qrow = lane & 15, grp = lane >> 4;

  const bf16* qb = q + (size_t)bh * NS * NHD;
  bf16x8 qfA[2], qfB[2];
#pragma unroll
  for (int ch = 0; ch < 2; ++ch) {
    qfA[ch] = *(const bf16x8*)&qb[(size_t)(q0A + qrow) * NHD + ch * 32 + grp * 8];
    qfB[ch] = *(const bf16x8*)&qb[(size_t)(q0B + qrow) * NHD + ch * 32 + grp * 8];
  }

  f32x4 oA[4] = {}, oB[4] = {};
  float mA = -1e30f, lA = 0.f, mB = -1e30f, lB = 0.f;

  const bf16* kb = k + (size_t)bh * NS * NHD;
  const bf16* vb = vt + (size_t)bh * NHD * NS;
  const int ktA = qtA + 1;          // iterations where tile A is active
  const int ktiles = qtB + 1;       // total iterations (B's range)

  const int sr  = threadIdx.x >> 3;         // staging row 0..31 (and +32)
  const int sc8 = (threadIdx.x & 7) * 8;    // staging col (x8 bf16)

  // prologue: stage tile 0
  {
    bf16x8 a = *(const bf16x8*)&kb[(size_t)sr * NHD + sc8];
    bf16x8 c = *(const bf16x8*)&kb[(size_t)(sr + 32) * NHD + sc8];
    bf16x8 d = *(const bf16x8*)&vb[(size_t)sr * NS + sc8];
    bf16x8 e = *(const bf16x8*)&vb[(size_t)(sr + 32) * NS + sc8];
    *(bf16x8*)&Ks[0][sr][sc8] = a;  *(bf16x8*)&Ks[0][sr + 32][sc8] = c;
    *(bf16x8*)&Vs[0][sr][sc8] = d;  *(bf16x8*)&Vs[0][sr + 32][sc8] = e;
  }

  bf16x8 kr0, kr1, vr0, vr1;
  for (int kt = 0; kt < ktiles; ++kt) {
    const int cur = kt & 1;
    const bool pre = (kt + 1 < ktiles);
    if (pre) {   // issue next-tile loads; latency hides under barrier+compute
      const int kn = (kt + 1) * 64;
      kr0 = *(const bf16x8*)&kb[(size_t)(kn + sr) * NHD + sc8];
      kr1 = *(const bf16x8*)&kb[(size_t)(kn + sr + 32) * NHD + sc8];
      vr0 = *(const bf16x8*)&vb[(size_t)sr * NS + kn + sc8];
      vr1 = *(const bf16x8*)&vb[(size_t)(sr + 32) * NS + kn + sc8];
    }
    block_sync_lds();   // publishes buf[cur]; in-flight global loads survive

    const bool actA = (kt < ktA);
    f32x4 sA[4] = {}, sB[4] = {};

    __builtin_amdgcn_s_setprio(1);
#pragma unroll
    for (int ch = 0; ch < 2; ++ch) {
#pragma unroll
      for (int cb = 0; cb < 4; ++cb) {
        bf16x8 kf = *(const bf16x8*)&Ks[cur][cb * 16 + qrow][ch * 32 + grp * 8];
        sB[cb] = MFMA16(kf, qfB[ch], sB[cb]);          // S^T[k][q]
        if (actA) sA[cb] = MFMA16(kf, qfA[ch], sA[cb]);
      }
    }
    __builtin_amdgcn_s_setprio(0);

    const int kk0 = kt * 64;
    if (kt == ktiles - 1) {          // B's diagonal tile
      const int qi = q0B + qrow;
#pragma unroll
      for (int cb = 0; cb < 4; ++cb)
#pragma unroll
        for (int r = 0; r < 4; ++r)
          if (kk0 + cb * 16 + grp * 4 + r > qi) sB[cb][r] = -1e30f;
    }
    if (actA && kt == ktA - 1) {     // A's diagonal tile
      const int qi = q0A + qrow;
#pragma unroll
      for (int cb = 0; cb < 4; ++cb)
#pragma unroll
        for (int r = 0; r < 4; ++r)
          if (kk0 + cb * 16 + grp * 4 + r > qi) sA[cb][r] = -1e30f;
    }

    // ---- online softmax B (base-2; lane owns q-row, 16 S values) ----
    {
      float pm = sB[0][0];
#pragma unroll
      for (int cb = 0; cb < 4; ++cb)
#pragma unroll
        for (int r = 0; r < 4; ++r) pm = fmaxf(pm, sB[cb][r]);
      pm = fmaxf(pm, __shfl_xor(pm, 16));
      pm = fmaxf(pm, __shfl_xor(pm, 32));
      const float mn = fmaxf(mB, pm);
      const float scl = exp2f(mB - mn);
      mB = mn;
      lB *= scl;
#pragma unroll
      for (int cb = 0; cb < 4; ++cb) {
        bf16x4 pk;
#pragma unroll
        for (int r = 0; r < 4; ++r) {
          float p = exp2f(sB[cb][r] - mn);
          lB += p;
          pk[r] = (bf16)p;
        }
        *(bf16x4*)&P[w][0][qrow][cb * 16 + grp * 4] = pk;
      }
#pragma unroll
      for (int hb = 0; hb < 4; ++hb)
#pragma unroll
        for (int r = 0; r < 4; ++r) oB[hb][r] *= scl;
    }

    // ---- online softmax A ----
    if (actA) {
      float pm = sA[0][0];
#pragma unroll
      for (int cb = 0; cb < 4; ++cb)
#pragma unroll
        for (int r = 0; r < 4; ++r) pm = fmaxf(pm, sA[cb][r]);
      pm = fmaxf(pm, __shfl_xor(pm, 16));
      pm = fmaxf(pm, __shfl_xor(pm, 32));
      const float mn = fmaxf(mA, pm);
      const float scl = exp2f(mA - mn);
      mA = mn;
      lA *= scl;
#pragma unroll
      for (int cb = 0; cb < 4; ++cb) {
        bf16x4 pk;
#pragma unroll
        for (int r = 0; r < 4; ++r) {
          float p = exp2f(sA[cb][r] - mn);
          lA += p;
          pk[r] = (bf16)p;
        }
        *(bf16x4*)&P[w][1][qrow][cb * 16 + grp * 4] = pk;
      }
#pragma unroll
      for (int hb = 0; hb < 4; ++hb)
#pragma unroll
        for (int r = 0; r < 4; ++r) oA[hb][r] *= scl;
    }

    // ---- PV for both tiles, shared V-fragment loads ----
    __builtin_amdgcn_s_setprio(1);
#pragma unroll
    for (int ch = 0; ch < 2; ++ch) {
      bf16x8 paB = *(const bf16x8*)&P[w][0][qrow][ch * 32 + grp * 8];
      bf16x8 paA;
      if (actA) paA = *(const bf16x8*)&P[w][1][qrow][ch * 32 + grp * 8];
#pragma unroll
      for (int hb = 0; hb < 4; ++hb) {
        bf16x8 vf = *(const bf16x8*)&Vs[cur][hb * 16 + qrow][ch * 32 + grp * 8];
        oB[hb] = MFMA16(vf, paB, oB[hb]);              // O^T[hd][q]
        if (actA) oA[hb] = MFMA16(vf, paA, oA[hb]);
      }
    }
    __builtin_amdgcn_s_setprio(0);

    if (pre) {   // write next tile into the other buffer (published next iter)
      *(bf16x8*)&Ks[cur ^ 1][sr][sc8] = kr0;
      *(bf16x8*)&Ks[cur ^ 1][sr + 32][sc8] = kr1;
      *(bf16x8*)&Vs[cur ^ 1][sr][sc8] = vr0;
      *(bf16x8*)&Vs[cur ^ 1][sr + 32][sc8] = vr1;
    }
  }

  // ---- epilogue: normalize + store both q-tiles ----
  lB += __shfl_xor(lB, 16);
  lB += __shfl_xor(lB, 32);
  {
    const float inv = 1.f / lB;
    const int s = q0B + qrow;
    bf16* op = out + (size_t)(b * NS + s) * ND + h * NHD + grp * 4;
#pragma unroll
    for (int hb = 0; hb < 4; ++hb) {
      bf16x4 ov = { (bf16)(oB[hb][0] * inv), (bf16)(oB[hb][1] * inv),
                    (bf16)(oB[hb][2] * inv), (bf16)(oB[hb][3] * inv) };
      *(bf16x4*)&op[hb * 16] = ov;
    }
  }
  lA += __shfl_xor(lA, 16);
  lA += __shfl_xor(lA, 32);
  {
    const float inv = 1.f / lA;
    const int s = q0A + qrow;
    bf16* op = out + (size_t)(b * NS + s) * ND + h * NHD + grp * 4;
#pragma unroll
    for (int hb = 0; hb < 4; ++hb) {
      bf16x4 ov = { (bf16)(oA[hb][0] * inv), (bf16)(oA[hb][1] * inv),
                    (bf16)(oA[hb][2] * inv), (bf16)(oA[hb][3] * inv) };
      *(bf16x4*)&op[hb * 16] = ov;
    }
  }
}

// -------------------------------------------------------------------------
extern "C" void kernel_launch(void* const* d_in, const int* in_sizes, int n_in,
                              void* d_out, int out_size, void* d_ws, size_t ws_size,
                              hipStream_t stream) {
  const float* Q  = (const float*)d_in[0];
  const float* K  = (const float*)d_in[1];
  const float* V  = (const float*)d_in[2];
  // d_in[3] = mask (causal, known analytically -> unused)
  const float* fc = (const float*)d_in[4];
  const float* fs = (const float*)d_in[5];
  const float* wq = (const float*)d_in[6];
  const float* bq = (const float*)d_in[7];
  const float* wk = (const float*)d_in[8];
  const float* bk = (const float*)d_in[9];
  const float* wv = (const float*)d_in[10];
  const float* bv = (const float*)d_in[11];
  const float* wo = (const float*)d_in[12];
  const float* bo = (const float*)d_in[13];
  float* out = (float*)d_out;
  bf16* ws = (bf16*)d_ws;

  const size_t MB_ = 1024 * 1024;  // elements
  bf16* Qbf  = ws;                     // 3 x 4M elems (Q,K,V bf16)
  bf16* Wqkv = ws + 12 * MB_;          // 3 x 1M (wq, wk, wv)
  bf16* Wo   = ws + 15 * MB_;          // 1M
  bf16* qp   = ws + 16 * MB_;          // q' [BH,S,HD] 4M
  bf16* kp   = ws + 20 * MB_;          // k' 4M
  bf16* vp   = ws + 24 * MB_;          // v' 4M
  bf16* vtp  = ws + 28 * MB_;          // v transposed [BH,HD,S] 4M
  bf16* aout = ws + 32 * MB_;          // attention output [M, D] 4M

  cvt3<<<dim3(4096, 3), 256, 0, stream>>>(Q, K, V, Qbf, 1048576);
  cvt_w4<<<dim3(1024, 4), 256, 0, stream>>>(wq, wk, wv, wo, Wqkv, 262144);

  gemm_nt<0><<<dim3(8, 32, 3), 256, 0, stream>>>(Qbf, Wqkv, bq, bk, bv, fc, fs, qp, nullptr);

  transpose_v<<<dim3(32, 32), 256, 0, stream>>>(vp, vtp);

  attn_k<<<dim3(16, 32), 256, 0, stream>>>(qp, kp, vtp, aout);

  gemm_nt<1><<<dim3(8, 32, 1), 256, 0, stream>>>(aout, Wo, bo, bo, bo, fc, fs, nullptr, out);
}